// Round 18
// baseline (101.096 us; speedup 1.0000x reference)
//
#include <hip/hip_runtime.h>

#define BB 8
#define CC 64
#define HH 96
#define WW 96
#define OO 64
#define KK 3
#define K2 9
#define HW (HH*WW)      // 9216
#define NOFF 18
#define NJP 32          // j padded for MFMA
#define NPIX (BB*HW)    // 73728
#define MT 64           // pixels per fused block: 2 rows x 32 cols
#define NTILE (HW/MT)   // 144 tiles per image
#define NXCD 8
#define WR 6
#define WC 36
#define NWIN (WR*WC)    // 216 window pixel-rows, 128 B each (seg-swizzled)
#define OSTR 21         // offs row stride (floats); gcd(21,32)=1 -> conflict-free

typedef _Float16 f16;
typedef __attribute__((ext_vector_type(2))) _Float16 f16x2;
typedef __attribute__((ext_vector_type(4))) _Float16 f16x4;
typedef __attribute__((ext_vector_type(4))) float f32x4;
typedef __attribute__((ext_vector_type(2))) unsigned int uint2v;
typedef __attribute__((ext_vector_type(4))) unsigned int uint4v;

#define MFMA16(a,b,c) __builtin_amdgcn_mfma_f32_16x16x16f16(a,b,c,0,0,0)

__device__ __forceinline__ f16x2 bch(unsigned u) { return __builtin_bit_cast(f16x2, u); }
__device__ __forceinline__ unsigned bcu(f16x2 h) { return __builtin_bit_cast(unsigned, h); }
__device__ __forceinline__ f16x4 fq(unsigned a, unsigned b) {
  uint2v u = {a, b};
  return __builtin_bit_cast(f16x4, u);
}
__device__ __forceinline__ f16x4 fq2(uint2v u) { return __builtin_bit_cast(f16x4, u); }
__device__ __forceinline__ int xcd_remap(int bid, int per) {
  return (bid & 7) * per + (bid >> 3);
}

// ---------------- Kernel T: NCHW fp32 -> NHWC f16 (verified R5) -------------
__global__ __launch_bounds__(256) void transpose_kernel(
    const float* __restrict__ x, unsigned short* __restrict__ xt) {
  int t = threadIdx.x;
  int px = xcd_remap(blockIdx.x, NPIX / 64 / NXCD) * 64 + (t & 63);
  int cg = t >> 6;
  int b = px / HW, hw = px % HW;
  const float* xp = x + (size_t)b * CC * HW + (size_t)(cg * 16) * HW + hw;
  f16 r[16];
  #pragma unroll
  for (int i = 0; i < 16; ++i) r[i] = (f16)xp[i * HW];
  uint4v v0, v1;
  #pragma unroll
  for (int q = 0; q < 4; ++q) {
    f16x2 a = {r[q*2], r[q*2+1]};       v0[q] = bcu(a);
    f16x2 bq = {r[8+q*2], r[8+q*2+1]};  v1[q] = bcu(bq);
  }
  uint4v* dst = (uint4v*)(xt + (size_t)px * CC + cg * 16);
  dst[0] = v0; dst[1] = v1;
}

// ---------------- Kernel W: w_dcn -> wt [K2][O][C] f16 (verified) -----------
__global__ void wprep_kernel(const float* __restrict__ w_dcn,
                             unsigned short* __restrict__ wt) {
  int idx = blockIdx.x * 256 + threadIdx.x;
  int k = idx / (OO * CC);
  int o = (idx / CC) % OO;
  int c = idx % CC;
  f16 h = (f16)w_dcn[(o * CC + c) * K2 + k];
  wt[idx] = __builtin_bit_cast(unsigned short, h);
}

// -------- Kernel W2: w_off [18][64][9] fp32 -> wofp [9][32][64] f16 ---------
// j padded to 32 with zeros (MFMA N-tile padding)
__global__ void woffprep_kernel(const float* __restrict__ w_off,
                                unsigned short* __restrict__ wofp) {
  int idx = blockIdx.x * 256 + threadIdx.x;   // 9*32*64 = 18432
  if (idx >= K2 * NJP * CC) return;
  int kt = idx / (NJP * CC);
  int j = (idx / CC) % NJP;
  int c = idx % CC;
  f16 h = (f16)((j < NOFF) ? w_off[(j * CC + c) * K2 + kt] : 0.f);
  wofp[idx] = __builtin_bit_cast(unsigned short, h);
}

// ---------------- Kernel F: fused offconv(MFMA) + dcn(MFMA) -----------------
// 512 threads / 8 waves. Window 6x36 staged once, seg-swizzled, ZERO-filled
// for out-of-image rows (= conv zero-pad for P1; unobservable for dcn since
// invalid corners carry weight 0).
// P1: offconv as MFMA GEMM [64px,576]x[576,32p]: wave (m=wv&3, n=wv>>2) does
//     9 taps x 4 k-chunks = 36 MFMA; A from window (taps always in-window by
//     construction), B from global wofp (L1-hot). D -> offs[px][21] + b_off.
// P2: params in registers (R15/R17-verified math).
// P3: dcn taps K-split: group0 taps 0-4, group1 taps 5-8 (R17-verified).
// P4: f32 acc-reduce via LDS (accx aliases dead xwin), group0 stores.
#define XWIN_OFF 0
#define OFFS_OFF 27648
#define ACCX_OFF 0        // aliases xwin (dead after P3)
#define SMEM_SZ  33024

__global__ __launch_bounds__(512, 4) void fused_kernel(
    const unsigned short* __restrict__ xt,    // [B][HW][C] f16
    const unsigned short* __restrict__ wofp,  // [K2][32][C] f16
    const float* __restrict__ b_off,          // [18] fp32
    const unsigned short* __restrict__ wt,    // [K2][O][C] f16
    float* __restrict__ out) {
  __shared__ __align__(16) char smem[SMEM_SZ];
  char* xwin = smem + XWIN_OFF;              // 216 x 128 B, seg-swizzled
  float* offs = (float*)(smem + OFFS_OFF);   // [64][21]
  float* accx = (float*)(smem + ACCX_OFF);   // [64 o][68 px] (aliases xwin)

  int t = threadIdx.x;
  int blk = xcd_remap(blockIdx.x, NPIX / MT / NXCD);
  int b = blk / NTILE;
  int ti = blk % NTILE;
  int tr = ti / 3, tc = ti % 3;
  int h0 = tr * 2, w0 = tc * 32;
  int hw0 = h0 * WW + w0;

  const char* xb = (const char*)(xt + (size_t)b * HW * CC);

  // ---- P0: stage window, seg-swizzled, zero-fill out-of-image ----
  #pragma unroll
  for (int r = 0; r < 4; ++r) {
    int d = r * 512 + t;                     // 16-B chunk id, 1728 total
    if (d < NWIN * 8) {
      int row = d >> 3, sg = d & 7;
      int wr_ = row / WC, wc_ = row - wr_ * WC;
      int gy = h0 - 2 + wr_;
      int gx = w0 - 2 + wc_;
      uint4v v = (uint4v){0u, 0u, 0u, 0u};
      if (((unsigned)gy < HH) && ((unsigned)gx < WW))
        v = *(const uint4v*)(xb + (size_t)((gy * WW + gx) << 7) + (sg << 4));
      *(uint4v*)&xwin[row * 128 + ((sg ^ (row & 7)) << 4)] = v;
    }
  }
  __syncthreads();

  // wave geometry (verified R9/R12)
  int wv = t >> 6;
  int l  = t & 63;
  int lr = l & 15, lh = l >> 4;

  // ---- P1: offset conv via MFMA ----
  {
    int m = wv & 3, n = wv >> 2;             // 4 pixel-tiles x 2 j-tiles
    int p = m * 16 + lr;                     // A row = this lane's pixel
    int prow = ((p >> 5) + 1) * WC + (p & 31) + 1;  // window row at ky=kx=0
    f32x4 accO = (f32x4){0.f, 0.f, 0.f, 0.f};
    #pragma unroll
    for (int kt = 0; kt < K2; ++kt) {
      int wrow = prow + (kt / 3) * WC + (kt % 3);
      int rs = wrow & 7;
      const char* bp = (const char*)wofp + (size_t)(kt * NJP + n * 16 + lr) * (CC * 2);
      #pragma unroll
      for (int q = 0; q < 4; ++q) {
        uint2v a2 = *(const uint2v*)&xwin[wrow * 128
                      + ((((q << 1) + (lh >> 1)) ^ rs) << 4) + ((lh & 1) << 3)];
        uint2v b2 = *(const uint2v*)(bp + (q << 5) + (lh << 3));
        accO = MFMA16(fq2(a2), fq2(b2), accO);
      }
    }
    int j = n * 16 + lr;
    if (j < NOFF) {
      float bj = b_off[j];
      #pragma unroll
      for (int r = 0; r < 4; ++r) {
        int px = m * 16 + lh * 4 + r;        // D row = pixel (R9 map)
        offs[px * OSTR + j] = accO[r] + bj;
      }
    }
  }
  __syncthreads();

  // ---- P2: per-lane params for this group's taps (R15/R17 math) ----
  int grp = wv >> 2;
  int base = grp * 5;                  // g0: taps 0..4, g1: taps 5..8
  int cnt  = 5 - grp;
  int Ra = (wv & 3) * 16 + lr;
  int hpix = h0 + (Ra >> 5), wpix = w0 + (Ra & 31);
  int cB = lh * 32;

  unsigned po01[5], po23[5], pw01[5], pw23[5];
  unsigned emask = 0;
  #pragma unroll
  for (int i = 0; i < 5; ++i) {
    po01[i] = 0; po23[i] = 0; pw01[i] = 0; pw23[i] = 0;
    if (i < cnt) {
      int kt = base + i;
      int ky = kt / 3, kx = kt % 3;
      float py = offs[Ra * OSTR + 2 * kt]     + (float)(hpix - 1 + ky);
      float px = offs[Ra * OSTR + 2 * kt + 1] + (float)(wpix - 1 + kx);
      float y0f = floorf(py), x0f = floorf(px);
      float wy = py - y0f, wx = px - x0f;
      int y0 = (int)y0f, x0 = (int)x0f;
      int y1 = y0 + 1, x1 = x0 + 1;
      bool vy0 = (unsigned)y0 < HH, vy1 = (unsigned)y1 < HH;
      bool vx0 = (unsigned)x0 < WW, vx1 = (unsigned)x1 < WW;
      int cy0 = min(max(y0, 0), HH - 1), cy1 = min(max(y1, 0), HH - 1);
      int cx0 = min(max(x0, 0), WW - 1), cx1 = min(max(x1, 0), WW - 1);
      float g00 = (1.f - wy) * (1.f - wx) * ((vy0 && vx0) ? 1.f : 0.f);
      float g01 = (1.f - wy) * wx         * ((vy0 && vx1) ? 1.f : 0.f);
      float g10 = wy * (1.f - wx)         * ((vy1 && vx0) ? 1.f : 0.f);
      float g11 = wy * wx                 * ((vy1 && vx1) ? 1.f : 0.f);
      int ry0 = cy0 - (h0 - 2), ry1 = cy1 - (h0 - 2);
      int rx0 = cx0 - (w0 - 2), rx1 = cx1 - (w0 - 2);
      bool inw = ((unsigned)ry0 < WR) && ((unsigned)ry1 < WR) &&
                 ((unsigned)rx0 < WC) && ((unsigned)rx1 < WC);
      if (inw) {
        po01[i] = (unsigned)((ry0 * WC + rx0) << 7)
                | ((unsigned)((ry0 * WC + rx1) << 7) << 16);
        po23[i] = (unsigned)((ry1 * WC + rx0) << 7)
                | ((unsigned)((ry1 * WC + rx1) << 7) << 16);
      } else {
        po01[i] = (unsigned)(cy0 * WW + cx0)
                | ((unsigned)(cy0 * WW + cx1) << 16) | 0x80000000u;
        po23[i] = (unsigned)(cy1 * WW + cx0)
                | ((unsigned)(cy1 * WW + cx1) << 16);
        emask |= 1u << i;
      }
      f16x2 wa = {(f16)g00, (f16)g01};
      f16x2 wb = {(f16)g10, (f16)g11};
      pw01[i] = bcu(wa);
      pw23[i] = bcu(wb);
    }
  }

  f32x4 acc[4];
  #pragma unroll
  for (int nb = 0; nb < 4; ++nb) acc[nb] = (f32x4){0.f, 0.f, 0.f, 0.f};

  // ---- P3: dcn taps (R17-verified blend/MFMA; window reads swizzled) ----
  #define WREAD(bo, pos) (*(const uint4v*)&xwin[(bo) + ((pos) << 4)])
  if (__ballot(emask != 0) == 0ull) {
    #pragma unroll
    for (int i = 0; i < 5; ++i) {
      if (i < cnt) {
        unsigned e0 = po01[i], e1 = po23[i];
        int i0 = (int)(e0 & 0xffffu), i1 = (int)(e0 >> 16);
        int i2 = (int)(e1 & 0xffffu), i3 = (int)(e1 >> 16);
        int s0 = lh * 2;
        uint4v c0a = WREAD(i0, s0 ^ ((i0 >> 7) & 7));
        uint4v c0b = WREAD(i0, (s0 + 1) ^ ((i0 >> 7) & 7));
        uint4v c1a = WREAD(i1, s0 ^ ((i1 >> 7) & 7));
        uint4v c1b = WREAD(i1, (s0 + 1) ^ ((i1 >> 7) & 7));
        uint4v c2a = WREAD(i2, s0 ^ ((i2 >> 7) & 7));
        uint4v c2b = WREAD(i2, (s0 + 1) ^ ((i2 >> 7) & 7));
        uint4v c3a = WREAD(i3, s0 ^ ((i3 >> 7) & 7));
        uint4v c3b = WREAD(i3, (s0 + 1) ^ ((i3 >> 7) & 7));
        f16x2 wA = bch(pw01[i]), wB = bch(pw23[i]);
        f16x2 p0 = {wA[0], wA[0]}, p1 = {wA[1], wA[1]};
        f16x2 p2 = {wB[0], wB[0]}, p3 = {wB[1], wB[1]};
        uint4v pa, pb2;
        #pragma unroll
        for (int q = 0; q < 4; ++q) {
          f16x2 s  = p0 * bch(c0a[q]) + p1 * bch(c1a[q])
                   + p2 * bch(c2a[q]) + p3 * bch(c3a[q]);
          pa[q] = bcu(s);
          f16x2 s2 = p0 * bch(c0b[q]) + p1 * bch(c1b[q])
                   + p2 * bch(c2b[q]) + p3 * bch(c3b[q]);
          pb2[q] = bcu(s2);
        }
        f16x4 a0 = fq(pa[0],  pa[1]);
        f16x4 a1 = fq(pa[2],  pa[3]);
        f16x4 a2 = fq(pb2[0], pb2[1]);
        f16x4 a3 = fq(pb2[2], pb2[3]);
        const char* wrow = (const char*)wt + (size_t)(base + i) * OO * (CC * 2);
        #pragma unroll
        for (int nb = 0; nb < 4; ++nb) {
          const char* wp = wrow + (size_t)(nb * 16 + lr) * (CC * 2) + cB;
          uint4v u0 = *(const uint4v*)wp;
          uint4v u1 = *(const uint4v*)(wp + 16);
          acc[nb] = MFMA16(a0, fq(u0[0], u0[1]), acc[nb]);
          acc[nb] = MFMA16(a1, fq(u0[2], u0[3]), acc[nb]);
          acc[nb] = MFMA16(a2, fq(u1[0], u1[1]), acc[nb]);
          acc[nb] = MFMA16(a3, fq(u1[2], u1[3]), acc[nb]);
        }
      }
    }
  } else {
    #pragma unroll
    for (int i = 0; i < 5; ++i) {
      if (i < cnt) {
        unsigned e0 = po01[i], e1 = po23[i];
        uint4v c0a, c0b, c1a, c1b, c2a, c2b, c3a, c3b;
        if ((int)e0 >= 0) {
          int i0 = (int)(e0 & 0xffffu), i1 = (int)(e0 >> 16);
          int i2 = (int)(e1 & 0xffffu), i3 = (int)(e1 >> 16);
          int s0 = lh * 2;
          c0a = WREAD(i0, s0 ^ ((i0 >> 7) & 7));
          c0b = WREAD(i0, (s0 + 1) ^ ((i0 >> 7) & 7));
          c1a = WREAD(i1, s0 ^ ((i1 >> 7) & 7));
          c1b = WREAD(i1, (s0 + 1) ^ ((i1 >> 7) & 7));
          c2a = WREAD(i2, s0 ^ ((i2 >> 7) & 7));
          c2b = WREAD(i2, (s0 + 1) ^ ((i2 >> 7) & 7));
          c3a = WREAD(i3, s0 ^ ((i3 >> 7) & 7));
          c3b = WREAD(i3, (s0 + 1) ^ ((i3 >> 7) & 7));
        } else {
          int i0 = (int)(e0 & 0x7fffu) << 7;
          int i1 = (int)((e0 >> 16) & 0x7fffu) << 7;
          int i2 = (int)(e1 & 0x7fffu) << 7;
          int i3 = (int)((e1 >> 16) & 0x7fffu) << 7;
          c0a = *(const uint4v*)(xb + i0 + cB);
          c0b = *(const uint4v*)(xb + i0 + cB + 16);
          c1a = *(const uint4v*)(xb + i1 + cB);
          c1b = *(const uint4v*)(xb + i1 + cB + 16);
          c2a = *(const uint4v*)(xb + i2 + cB);
          c2b = *(const uint4v*)(xb + i2 + cB + 16);
          c3a = *(const uint4v*)(xb + i3 + cB);
          c3b = *(const uint4v*)(xb + i3 + cB + 16);
        }
        f16x2 wA = bch(pw01[i]), wB = bch(pw23[i]);
        f16x2 p0 = {wA[0], wA[0]}, p1 = {wA[1], wA[1]};
        f16x2 p2 = {wB[0], wB[0]}, p3 = {wB[1], wB[1]};
        uint4v pa, pb2;
        #pragma unroll
        for (int q = 0; q < 4; ++q) {
          f16x2 s  = p0 * bch(c0a[q]) + p1 * bch(c1a[q])
                   + p2 * bch(c2a[q]) + p3 * bch(c3a[q]);
          pa[q] = bcu(s);
          f16x2 s2 = p0 * bch(c0b[q]) + p1 * bch(c1b[q])
                   + p2 * bch(c2b[q]) + p3 * bch(c3b[q]);
          pb2[q] = bcu(s2);
        }
        f16x4 a0 = fq(pa[0],  pa[1]);
        f16x4 a1 = fq(pa[2],  pa[3]);
        f16x4 a2 = fq(pb2[0], pb2[1]);
        f16x4 a3 = fq(pb2[2], pb2[3]);
        const char* wrow = (const char*)wt + (size_t)(base + i) * OO * (CC * 2);
        #pragma unroll
        for (int nb = 0; nb < 4; ++nb) {
          const char* wp = wrow + (size_t)(nb * 16 + lr) * (CC * 2) + cB;
          uint4v u0 = *(const uint4v*)wp;
          uint4v u1 = *(const uint4v*)(wp + 16);
          acc[nb] = MFMA16(a0, fq(u0[0], u0[1]), acc[nb]);
          acc[nb] = MFMA16(a1, fq(u0[2], u0[3]), acc[nb]);
          acc[nb] = MFMA16(a2, fq(u1[0], u1[1]), acc[nb]);
          acc[nb] = MFMA16(a3, fq(u1[2], u1[3]), acc[nb]);
        }
      }
    }
  }
  __syncthreads();   // xwin dead; accx (alias) exchange

  // ---- P4: group1 -> accx, group0 adds + stores ----
  if (grp == 1) {
    #pragma unroll
    for (int nb = 0; nb < 4; ++nb)
      *(f32x4*)&accx[(nb * 16 + lr) * 68 + (wv & 3) * 16 + lh * 4] = acc[nb];
  }
  __syncthreads();
  if (grp == 0) {
    float* ob = out + (size_t)b * OO * HW;
    #pragma unroll
    for (int nb = 0; nb < 4; ++nb) {
      f32x4 other = *(const f32x4*)&accx[(nb * 16 + lr) * 68 + (wv & 3) * 16 + lh * 4];
      f32x4 v = acc[nb] + other;
      int o = nb * 16 + lr;
      int m = (wv & 3) * 16 + lh * 4;
      int base2 = hw0 + (m >> 5) * WW + (m & 31);
      *(f32x4*)(ob + (size_t)o * HW + base2) = v;
    }
  }
}

extern "C" void kernel_launch(void* const* d_in, const int* in_sizes, int n_in,
                              void* d_out, int out_size, void* d_ws, size_t ws_size,
                              hipStream_t stream) {
  const float* x     = (const float*)d_in[0];
  const float* w_off = (const float*)d_in[1];
  const float* b_off = (const float*)d_in[2];
  const float* w_dcn = (const float*)d_in[3];
  float* out = (float*)d_out;

  char* ws = (char*)d_ws;
  unsigned short* xtp = (unsigned short*)ws;                     // 9,437,184 B
  unsigned short* wtp = (unsigned short*)(ws + 9437184);         //    73,728 B
  unsigned short* wofp = (unsigned short*)(ws + 9437184 + 73728);//    36,864 B

  transpose_kernel<<<NPIX / 64, 256, 0, stream>>>(x, xtp);
  wprep_kernel<<<(K2 * OO * CC) / 256, 256, 0, stream>>>(w_dcn, wtp);
  woffprep_kernel<<<(K2 * NJP * CC + 255) / 256, 256, 0, stream>>>(w_off, wofp);
  fused_kernel<<<NPIX / MT, 512, 0, stream>>>(xtp, wofp, b_off, wtp, out);
}

// Round 19
// 67.382 us; speedup vs baseline: 1.5003x; 1.5003x over previous
//
#include <hip/hip_runtime.h>

#define BB 8
#define CC 64
#define HH 96
#define WW 96
#define OO 64
#define KK 3
#define K2 9
#define HW (HH*WW)      // 9216
#define NOFF 18
#define NPIX (BB*HW)    // 73728
#define MT 64           // pixels per fused block: 2 rows x 32 cols
#define NTILE (HW/MT)   // 144 tiles per image
#define NXCD 8
#define WR 6
#define WC 36
#define NWIN (WR*WC)    // 216 window pixel-rows, 128 B each (seg-swizzled)

typedef _Float16 f16;
typedef __attribute__((ext_vector_type(2))) _Float16 f16x2;
typedef __attribute__((ext_vector_type(4))) _Float16 f16x4;
typedef __attribute__((ext_vector_type(4))) float f32x4;
typedef __attribute__((ext_vector_type(2))) unsigned int uint2v;
typedef __attribute__((ext_vector_type(4))) unsigned int uint4v;

#define MFMA16(a,b,c) __builtin_amdgcn_mfma_f32_16x16x16f16(a,b,c,0,0,0)

#if __has_builtin(__builtin_amdgcn_fdot2)
__device__ __forceinline__ float dot2u(unsigned a, unsigned b, float c) {
  return __builtin_amdgcn_fdot2(__builtin_bit_cast(f16x2, a),
                                __builtin_bit_cast(f16x2, b), c, false);
}
#else
__device__ __forceinline__ float dot2u(unsigned a, unsigned b, float c) {
  f16x2 ha = __builtin_bit_cast(f16x2, a), hb = __builtin_bit_cast(f16x2, b);
  return c + (float)ha[0] * (float)hb[0] + (float)ha[1] * (float)hb[1];
}
#endif

__device__ __forceinline__ f16x2 bch(unsigned u) { return __builtin_bit_cast(f16x2, u); }
__device__ __forceinline__ unsigned bcu(f16x2 h) { return __builtin_bit_cast(unsigned, h); }
__device__ __forceinline__ f16x4 fq(unsigned a, unsigned b) {
  uint2v u = {a, b};
  return __builtin_bit_cast(f16x4, u);
}
__device__ __forceinline__ int xcd_remap(int bid, int per) {
  return (bid & 7) * per + (bid >> 3);
}

// ---------------- Kernel T: NCHW fp32 -> NHWC f16 (verified R5) -------------
__global__ __launch_bounds__(256) void transpose_kernel(
    const float* __restrict__ x, unsigned short* __restrict__ xt) {
  int t = threadIdx.x;
  int px = xcd_remap(blockIdx.x, NPIX / 64 / NXCD) * 64 + (t & 63);
  int cg = t >> 6;
  int b = px / HW, hw = px % HW;
  const float* xp = x + (size_t)b * CC * HW + (size_t)(cg * 16) * HW + hw;
  f16 r[16];
  #pragma unroll
  for (int i = 0; i < 16; ++i) r[i] = (f16)xp[i * HW];
  uint4v v0, v1;
  #pragma unroll
  for (int q = 0; q < 4; ++q) {
    f16x2 a = {r[q*2], r[q*2+1]};       v0[q] = bcu(a);
    f16x2 bq = {r[8+q*2], r[8+q*2+1]};  v1[q] = bcu(bq);
  }
  uint4v* dst = (uint4v*)(xt + (size_t)px * CC + cg * 16);
  dst[0] = v0; dst[1] = v1;
}

// ------- Kernel W: w_dcn -> wtx[k][nb][l][16 ch] f16, lane-exact layout -----
// Entry (k, nb, l) holds channels 16*(l>>4) + 0..15 of out-chan nb*16+(l&15):
// exactly lane l's B-fragment -> wave reads 2 KB contiguous per (k,nb).
__global__ void wprep_kernel(const float* __restrict__ w_dcn,
                             unsigned short* __restrict__ wtx) {
  int idx = blockIdx.x * 256 + threadIdx.x;   // 9*4*64*16 = 36864
  int e = idx & 15;                            // channel within fragment
  int l = (idx >> 4) & 63;
  int nb = (idx >> 10) & 3;
  int k = idx >> 12;
  int c = 16 * (l >> 4) + e;
  int o = nb * 16 + (l & 15);
  f16 h = (f16)w_dcn[(o * CC + c) * K2 + k];
  wtx[idx] = __builtin_bit_cast(unsigned short, h);
}

// ---------------- Kernel W2: w_off [18][64][9] fp32 -> wof [9][18][64] f16 --
__global__ void woffprep_kernel(const float* __restrict__ w_off,
                                unsigned short* __restrict__ wof) {
  int idx = blockIdx.x * 256 + threadIdx.x;   // 9*18*64 = 10368
  if (idx >= K2 * NOFF * CC) return;
  int kt = idx / (NOFF * CC);
  int j = (idx / CC) % NOFF;
  int c = idx % CC;
  f16 h = (f16)w_off[(j * CC + c) * K2 + kt];
  wof[idx] = __builtin_bit_cast(unsigned short, h);
}

// ---------------- Kernel F: fused offconv + dcn (R17 base + wtx B-loads) ----
#define XWIN_OFF 0
#define WL_OFF   27648
#define OFFS_OFF 48384
#define ACCX_OFF WL_OFF   // accx aliases wl (dead after P1)
#define SMEM_SZ  52992

__global__ __launch_bounds__(512, 4) void fused_kernel(
    const unsigned short* __restrict__ xt,   // [B][HW][C] f16
    const unsigned short* __restrict__ wof,  // [K2][18][C] f16
    const float* __restrict__ b_off,         // [18] fp32
    const unsigned short* __restrict__ wtx,  // [K2][4][64][16] f16 lane-exact
    float* __restrict__ out) {
  __shared__ __align__(16) char smem[SMEM_SZ];
  char* xwin = smem + XWIN_OFF;      // 216 x 128 B, seg-swizzled
  char* wl   = smem + WL_OFF;        // 162 x 128 B, seg-swizzled
  float* offs = (float*)(smem + OFFS_OFF);   // [64][18]
  float* accx = (float*)(smem + ACCX_OFF);   // [64 o][68 px] padded

  int t = threadIdx.x;
  int blk = xcd_remap(blockIdx.x, NPIX / MT / NXCD);
  int b = blk / NTILE;
  int ti = blk % NTILE;
  int tr = ti / 3, tc = ti % 3;
  int h0 = tr * 2, w0 = tc * 32;
  int hw0 = h0 * WW + w0;

  const char* xb = (const char*)(xt + (size_t)b * HW * CC);

  // ---- P0: stage window + w_off tile, seg-swizzled (verified R17) ----
  #pragma unroll
  for (int r = 0; r < 4; ++r) {
    int d = r * 512 + t;                     // 16-B chunk id, 1728 total
    if (d < NWIN * 8) {
      int row = d >> 3, sg = d & 7;
      int wr_ = row / WC, wc_ = row - wr_ * WC;
      int gy = min(max(h0 - 2 + wr_, 0), HH - 1);
      int gx = min(max(w0 - 2 + wc_, 0), WW - 1);
      uint4v v = *(const uint4v*)(xb + (size_t)((gy * WW + gx) << 7) + (sg << 4));
      *(uint4v*)&xwin[row * 128 + ((sg ^ (row & 7)) << 4)] = v;
    }
  }
  #pragma unroll
  for (int r = 0; r < 3; ++r) {
    int d = r * 512 + t;                     // 1296 total
    if (d < K2 * NOFF * 8) {
      int row = d >> 3, sg = d & 7;
      uint4v v = *(const uint4v*)((const char*)wof + (size_t)d * 16);
      *(uint4v*)&wl[row * 128 + ((sg ^ (row & 7)) << 4)] = v;
    }
  }
  __syncthreads();

  // ---- P1: offset conv (dot2, R5/R17-verified accumulation order) ----
  {
    int px = t >> 3, jg = t & 7;
    int hpix = h0 + (px >> 5), wpix = w0 + (px & 31);
    float ao[3];
    #pragma unroll
    for (int ji = 0; ji < 3; ++ji) {
      int j = jg + ji * 8;
      ao[ji] = (j < NOFF) ? b_off[j] : 0.f;
    }
    for (int kt = 0; kt < K2; ++kt) {
      int ky = kt / 3, kx = kt % 3;
      int y = hpix - 1 + ky, xx = wpix - 1 + kx;
      if (((unsigned)y < HH) && ((unsigned)xx < WW)) {
        int row = (y - (h0 - 2)) * WC + (xx - (w0 - 2));
        int rs = row & 7;
        uint4v xr[8];
        #pragma unroll
        for (int s = 0; s < 8; ++s)
          xr[s] = *(const uint4v*)&xwin[row * 128 + ((s ^ rs) << 4)];
        #pragma unroll
        for (int ji = 0; ji < 3; ++ji) {
          int j = jg + ji * 8;
          if (j < NOFF) {
            int row2 = kt * NOFF + j;
            int rs2 = row2 & 7;
            float a = ao[ji];
            #pragma unroll
            for (int s = 0; s < 8; ++s) {
              uint4v wv_ = *(const uint4v*)&wl[row2 * 128 + ((s ^ rs2) << 4)];
              a = dot2u(xr[s][0], wv_[0], a);
              a = dot2u(xr[s][1], wv_[1], a);
              a = dot2u(xr[s][2], wv_[2], a);
              a = dot2u(xr[s][3], wv_[3], a);
            }
            ao[ji] = a;
          }
        }
      }
    }
    #pragma unroll
    for (int ji = 0; ji < 3; ++ji) {
      int j = jg + ji * 8;
      if (j < NOFF) offs[px * NOFF + j] = ao[ji];
    }
  }
  __syncthreads();

  // ---- P2: per-lane params for this group's taps (R15/R17 math) ----
  int wv = t >> 6;
  int l  = t & 63;
  int lr = l & 15, lh = l >> 4;
  int grp = wv >> 2;
  int base = grp * 5;                  // g0: taps 0..4, g1: taps 5..8
  int cnt  = 5 - grp;
  int Ra = (wv & 3) * 16 + lr;
  int hpix = h0 + (Ra >> 5), wpix = w0 + (Ra & 31);
  int cB = lh * 32;

  unsigned po01[5], po23[5], pw01[5], pw23[5];
  unsigned emask = 0;
  #pragma unroll
  for (int i = 0; i < 5; ++i) {
    po01[i] = 0; po23[i] = 0; pw01[i] = 0; pw23[i] = 0;
    if (i < cnt) {
      int kt = base + i;
      int ky = kt / 3, kx = kt % 3;
      float py = offs[Ra * NOFF + 2 * kt]     + (float)(hpix - 1 + ky);
      float px = offs[Ra * NOFF + 2 * kt + 1] + (float)(wpix - 1 + kx);
      float y0f = floorf(py), x0f = floorf(px);
      float wy = py - y0f, wx = px - x0f;
      int y0 = (int)y0f, x0 = (int)x0f;
      int y1 = y0 + 1, x1 = x0 + 1;
      bool vy0 = (unsigned)y0 < HH, vy1 = (unsigned)y1 < HH;
      bool vx0 = (unsigned)x0 < WW, vx1 = (unsigned)x1 < WW;
      int cy0 = min(max(y0, 0), HH - 1), cy1 = min(max(y1, 0), HH - 1);
      int cx0 = min(max(x0, 0), WW - 1), cx1 = min(max(x1, 0), WW - 1);
      float g00 = (1.f - wy) * (1.f - wx) * ((vy0 && vx0) ? 1.f : 0.f);
      float g01 = (1.f - wy) * wx         * ((vy0 && vx1) ? 1.f : 0.f);
      float g10 = wy * (1.f - wx)         * ((vy1 && vx0) ? 1.f : 0.f);
      float g11 = wy * wx                 * ((vy1 && vx1) ? 1.f : 0.f);
      int ry0 = cy0 - (h0 - 2), ry1 = cy1 - (h0 - 2);
      int rx0 = cx0 - (w0 - 2), rx1 = cx1 - (w0 - 2);
      bool inw = ((unsigned)ry0 < WR) && ((unsigned)ry1 < WR) &&
                 ((unsigned)rx0 < WC) && ((unsigned)rx1 < WC);
      if (inw) {   // window byte bases (<27648, fits 15 bits)
        po01[i] = (unsigned)((ry0 * WC + rx0) << 7)
                | ((unsigned)((ry0 * WC + rx1) << 7) << 16);
        po23[i] = (unsigned)((ry1 * WC + rx0) << 7)
                | ((unsigned)((ry1 * WC + rx1) << 7) << 16);
      } else {
        po01[i] = (unsigned)(cy0 * WW + cx0)
                | ((unsigned)(cy0 * WW + cx1) << 16) | 0x80000000u;
        po23[i] = (unsigned)(cy1 * WW + cx0)
                | ((unsigned)(cy1 * WW + cx1) << 16);
        emask |= 1u << i;
      }
      f16x2 wa = {(f16)g00, (f16)g01};
      f16x2 wb = {(f16)g10, (f16)g11};
      pw01[i] = bcu(wa);
      pw23[i] = bcu(wb);
    }
  }

  f32x4 acc[4];
  #pragma unroll
  for (int nb = 0; nb < 4; ++nb) acc[nb] = (f32x4){0.f, 0.f, 0.f, 0.f};

  // ---- P3: dcn taps (R17 blend/MFMA; B via lane-exact wtx, coalesced) ----
  #define WREAD(bo, pos) (*(const uint4v*)&xwin[(bo) + ((pos) << 4)])
  if (__ballot(emask != 0) == 0ull) {
    #pragma unroll
    for (int i = 0; i < 5; ++i) {
      if (i < cnt) {
        unsigned e0 = po01[i], e1 = po23[i];
        int i0 = (int)(e0 & 0xffffu), i1 = (int)(e0 >> 16);
        int i2 = (int)(e1 & 0xffffu), i3 = (int)(e1 >> 16);
        int s0 = lh * 2;
        uint4v c0a = WREAD(i0, s0 ^ ((i0 >> 7) & 7));
        uint4v c0b = WREAD(i0, (s0 + 1) ^ ((i0 >> 7) & 7));
        uint4v c1a = WREAD(i1, s0 ^ ((i1 >> 7) & 7));
        uint4v c1b = WREAD(i1, (s0 + 1) ^ ((i1 >> 7) & 7));
        uint4v c2a = WREAD(i2, s0 ^ ((i2 >> 7) & 7));
        uint4v c2b = WREAD(i2, (s0 + 1) ^ ((i2 >> 7) & 7));
        uint4v c3a = WREAD(i3, s0 ^ ((i3 >> 7) & 7));
        uint4v c3b = WREAD(i3, (s0 + 1) ^ ((i3 >> 7) & 7));
        f16x2 wA = bch(pw01[i]), wB = bch(pw23[i]);
        f16x2 p0 = {wA[0], wA[0]}, p1 = {wA[1], wA[1]};
        f16x2 p2 = {wB[0], wB[0]}, p3 = {wB[1], wB[1]};
        uint4v pa, pb2;
        #pragma unroll
        for (int q = 0; q < 4; ++q) {
          f16x2 s  = p0 * bch(c0a[q]) + p1 * bch(c1a[q])
                   + p2 * bch(c2a[q]) + p3 * bch(c3a[q]);
          pa[q] = bcu(s);
          f16x2 s2 = p0 * bch(c0b[q]) + p1 * bch(c1b[q])
                   + p2 * bch(c2b[q]) + p3 * bch(c3b[q]);
          pb2[q] = bcu(s2);
        }
        f16x4 a0 = fq(pa[0],  pa[1]);
        f16x4 a1 = fq(pa[2],  pa[3]);
        f16x4 a2 = fq(pb2[0], pb2[1]);
        f16x4 a3 = fq(pb2[2], pb2[3]);
        const char* wbase = (const char*)wtx
                          + (((size_t)(base + i) * 4) * 64 + l) * 32;
        #pragma unroll
        for (int nb = 0; nb < 4; ++nb) {
          const char* wp = wbase + (size_t)nb * (64 * 32);
          uint4v u0 = *(const uint4v*)wp;
          uint4v u1 = *(const uint4v*)(wp + 16);
          acc[nb] = MFMA16(a0, fq(u0[0], u0[1]), acc[nb]);
          acc[nb] = MFMA16(a1, fq(u0[2], u0[3]), acc[nb]);
          acc[nb] = MFMA16(a2, fq(u1[0], u1[1]), acc[nb]);
          acc[nb] = MFMA16(a3, fq(u1[2], u1[3]), acc[nb]);
        }
      }
    }
  } else {
    #pragma unroll
    for (int i = 0; i < 5; ++i) {
      if (i < cnt) {
        unsigned e0 = po01[i], e1 = po23[i];
        uint4v c0a, c0b, c1a, c1b, c2a, c2b, c3a, c3b;
        if ((int)e0 >= 0) {
          int i0 = (int)(e0 & 0xffffu), i1 = (int)(e0 >> 16);
          int i2 = (int)(e1 & 0xffffu), i3 = (int)(e1 >> 16);
          int s0 = lh * 2;
          c0a = WREAD(i0, s0 ^ ((i0 >> 7) & 7));
          c0b = WREAD(i0, (s0 + 1) ^ ((i0 >> 7) & 7));
          c1a = WREAD(i1, s0 ^ ((i1 >> 7) & 7));
          c1b = WREAD(i1, (s0 + 1) ^ ((i1 >> 7) & 7));
          c2a = WREAD(i2, s0 ^ ((i2 >> 7) & 7));
          c2b = WREAD(i2, (s0 + 1) ^ ((i2 >> 7) & 7));
          c3a = WREAD(i3, s0 ^ ((i3 >> 7) & 7));
          c3b = WREAD(i3, (s0 + 1) ^ ((i3 >> 7) & 7));
        } else {
          int i0 = (int)(e0 & 0x7fffu) << 7;
          int i1 = (int)((e0 >> 16) & 0x7fffu) << 7;
          int i2 = (int)(e1 & 0x7fffu) << 7;
          int i3 = (int)((e1 >> 16) & 0x7fffu) << 7;
          c0a = *(const uint4v*)(xb + i0 + cB);
          c0b = *(const uint4v*)(xb + i0 + cB + 16);
          c1a = *(const uint4v*)(xb + i1 + cB);
          c1b = *(const uint4v*)(xb + i1 + cB + 16);
          c2a = *(const uint4v*)(xb + i2 + cB);
          c2b = *(const uint4v*)(xb + i2 + cB + 16);
          c3a = *(const uint4v*)(xb + i3 + cB);
          c3b = *(const uint4v*)(xb + i3 + cB + 16);
        }
        f16x2 wA = bch(pw01[i]), wB = bch(pw23[i]);
        f16x2 p0 = {wA[0], wA[0]}, p1 = {wA[1], wA[1]};
        f16x2 p2 = {wB[0], wB[0]}, p3 = {wB[1], wB[1]};
        uint4v pa, pb2;
        #pragma unroll
        for (int q = 0; q < 4; ++q) {
          f16x2 s  = p0 * bch(c0a[q]) + p1 * bch(c1a[q])
                   + p2 * bch(c2a[q]) + p3 * bch(c3a[q]);
          pa[q] = bcu(s);
          f16x2 s2 = p0 * bch(c0b[q]) + p1 * bch(c1b[q])
                   + p2 * bch(c2b[q]) + p3 * bch(c3b[q]);
          pb2[q] = bcu(s2);
        }
        f16x4 a0 = fq(pa[0],  pa[1]);
        f16x4 a1 = fq(pa[2],  pa[3]);
        f16x4 a2 = fq(pb2[0], pb2[1]);
        f16x4 a3 = fq(pb2[2], pb2[3]);
        const char* wbase = (const char*)wtx
                          + (((size_t)(base + i) * 4) * 64 + l) * 32;
        #pragma unroll
        for (int nb = 0; nb < 4; ++nb) {
          const char* wp = wbase + (size_t)nb * (64 * 32);
          uint4v u0 = *(const uint4v*)wp;
          uint4v u1 = *(const uint4v*)(wp + 16);
          acc[nb] = MFMA16(a0, fq(u0[0], u0[1]), acc[nb]);
          acc[nb] = MFMA16(a1, fq(u0[2], u0[3]), acc[nb]);
          acc[nb] = MFMA16(a2, fq(u1[0], u1[1]), acc[nb]);
          acc[nb] = MFMA16(a3, fq(u1[2], u1[3]), acc[nb]);
        }
      }
    }
  }
  __syncthreads();   // window/wl dead; accx (alias wl) exchange

  // ---- P4: group1 -> accx, group0 adds + stores (verified R17) ----
  if (grp == 1) {
    #pragma unroll
    for (int nb = 0; nb < 4; ++nb)
      *(f32x4*)&accx[(nb * 16 + lr) * 68 + (wv & 3) * 16 + lh * 4] = acc[nb];
  }
  __syncthreads();
  if (grp == 0) {
    float* ob = out + (size_t)b * OO * HW;
    #pragma unroll
    for (int nb = 0; nb < 4; ++nb) {
      f32x4 other = *(const f32x4*)&accx[(nb * 16 + lr) * 68 + (wv & 3) * 16 + lh * 4];
      f32x4 v = acc[nb] + other;
      int o = nb * 16 + lr;
      int m = (wv & 3) * 16 + lh * 4;
      int base2 = hw0 + (m >> 5) * WW + (m & 31);
      *(f32x4*)(ob + (size_t)o * HW + base2) = v;
    }
  }
}

extern "C" void kernel_launch(void* const* d_in, const int* in_sizes, int n_in,
                              void* d_out, int out_size, void* d_ws, size_t ws_size,
                              hipStream_t stream) {
  const float* x     = (const float*)d_in[0];
  const float* w_off = (const float*)d_in[1];
  const float* b_off = (const float*)d_in[2];
  const float* w_dcn = (const float*)d_in[3];
  float* out = (float*)d_out;

  char* ws = (char*)d_ws;
  unsigned short* xtp = (unsigned short*)ws;                     // 9,437,184 B
  unsigned short* wtx = (unsigned short*)(ws + 9437184);         //    73,728 B
  unsigned short* wof = (unsigned short*)(ws + 9437184 + 73728); //    20,736 B

  transpose_kernel<<<NPIX / 64, 256, 0, stream>>>(x, xtp);
  wprep_kernel<<<(K2 * 4 * 64 * 16) / 256, 256, 0, stream>>>(w_dcn, wtx);
  woffprep_kernel<<<(K2 * NOFF * CC + 255) / 256, 256, 0, stream>>>(w_off, wof);
  fused_kernel<<<NPIX / MT, 512, 0, stream>>>(xtp, wof, b_off, wtx, out);
}

// Round 20
// 47.041 us; speedup vs baseline: 2.1491x; 1.4324x over previous
//
#include <hip/hip_runtime.h>

#define BB 8
#define CC 64
#define HH 96
#define WW 96
#define OO 64
#define KK 3
#define K2 9
#define HW (HH*WW)      // 9216
#define NOFF 18
#define NPIX (BB*HW)    // 73728
#define MT 64           // pixels per fused block: 2 rows x 32 cols
#define NTILE (HW/MT)   // 144 tiles per image
#define NXCD 8
#define WR 6
#define WC 36
#define NWIN (WR*WC)    // 216 window pixel-rows, 128 B each (seg-swizzled)
#define OSTR 21         // offs row stride (floats)

typedef _Float16 f16;
typedef __attribute__((ext_vector_type(2))) _Float16 f16x2;
typedef __attribute__((ext_vector_type(4))) _Float16 f16x4;
typedef __attribute__((ext_vector_type(4))) float f32x4;
typedef __attribute__((ext_vector_type(2))) unsigned int uint2v;
typedef __attribute__((ext_vector_type(4))) unsigned int uint4v;

#define MFMA16(a,b,c) __builtin_amdgcn_mfma_f32_16x16x16f16(a,b,c,0,0,0)

__device__ __forceinline__ f16x2 bch(unsigned u) { return __builtin_bit_cast(f16x2, u); }
__device__ __forceinline__ unsigned bcu(f16x2 h) { return __builtin_bit_cast(unsigned, h); }
__device__ __forceinline__ f16x4 fq(unsigned a, unsigned b) {
  uint2v u = {a, b};
  return __builtin_bit_cast(f16x4, u);
}
__device__ __forceinline__ f16x4 fq2(uint2v u) { return __builtin_bit_cast(f16x4, u); }
__device__ __forceinline__ int xcd_remap(int bid, int per) {
  return (bid & 7) * per + (bid >> 3);
}

// ---------------- Kernel T: NCHW fp32 -> NHWC f16 (verified R5) -------------
__global__ __launch_bounds__(256) void transpose_kernel(
    const float* __restrict__ x, unsigned short* __restrict__ xt) {
  int t = threadIdx.x;
  int px = xcd_remap(blockIdx.x, NPIX / 64 / NXCD) * 64 + (t & 63);
  int cg = t >> 6;
  int b = px / HW, hw = px % HW;
  const float* xp = x + (size_t)b * CC * HW + (size_t)(cg * 16) * HW + hw;
  f16 r[16];
  #pragma unroll
  for (int i = 0; i < 16; ++i) r[i] = (f16)xp[i * HW];
  uint4v v0, v1;
  #pragma unroll
  for (int q = 0; q < 4; ++q) {
    f16x2 a = {r[q*2], r[q*2+1]};       v0[q] = bcu(a);
    f16x2 bq = {r[8+q*2], r[8+q*2+1]};  v1[q] = bcu(bq);
  }
  uint4v* dst = (uint4v*)(xt + (size_t)px * CC + cg * 16);
  dst[0] = v0; dst[1] = v1;
}

// ------- Kernel W: w_dcn -> wtx[k][nb][l][16 ch] f16, lane-exact (R19) ------
__global__ void wprep_kernel(const float* __restrict__ w_dcn,
                             unsigned short* __restrict__ wtx) {
  int idx = blockIdx.x * 256 + threadIdx.x;   // 36864
  int e = idx & 15;
  int l = (idx >> 4) & 63;
  int nb = (idx >> 10) & 3;
  int k = idx >> 12;
  int c = 16 * (l >> 4) + e;
  int o = nb * 16 + (l & 15);
  f16 h = (f16)w_dcn[(o * CC + c) * K2 + k];
  wtx[idx] = __builtin_bit_cast(unsigned short, h);
}

// ----- Kernel W2: w_off -> wofx[kt][n][q][l][4 ch] f16, lane-exact ----------
// Entry (kt,n,q,l): channels c = 16q + 4*(l>>4) + e of j = n*16 + (l&15)
// (same kappa as the P1 A-side window read -> contraction exact); j>=18 -> 0.
__global__ void woffprep_kernel(const float* __restrict__ w_off,
                                unsigned short* __restrict__ wofx) {
  int idx = blockIdx.x * 256 + threadIdx.x;   // 9*2*4*64*4 = 18432
  int e = idx & 3;
  int l = (idx >> 2) & 63;
  int q = (idx >> 8) & 3;
  int n = (idx >> 10) & 1;
  int kt = idx >> 11;
  int c = q * 16 + 4 * (l >> 4) + e;
  int j = n * 16 + (l & 15);
  f16 h = (f16)((j < NOFF) ? w_off[(j * CC + c) * K2 + kt] : 0.f);
  wofx[idx] = __builtin_bit_cast(unsigned short, h);
}

// ---------------- Kernel F: fused offconv(MFMA) + dcn(MFMA) -----------------
// R18's P1-MFMA (passed, absmax 0.015625) + lane-exact wofx B (the R19 cure)
// + R19's P3 (wtx lane-exact dcn B). Window zero-filled (R18-verified: conv
// zero-pad for P1; unobservable for dcn since invalid corners carry g=0).
#define XWIN_OFF 0
#define OFFS_OFF 27648
#define ACCX_OFF 0        // aliases xwin (dead after P3)
#define SMEM_SZ  33024

__global__ __launch_bounds__(512, 4) void fused_kernel(
    const unsigned short* __restrict__ xt,    // [B][HW][C] f16
    const unsigned short* __restrict__ wofx,  // [K2][2][4][64][4] f16
    const float* __restrict__ b_off,          // [18] fp32
    const unsigned short* __restrict__ wtx,   // [K2][4][64][16] f16
    float* __restrict__ out) {
  __shared__ __align__(16) char smem[SMEM_SZ];
  char* xwin = smem + XWIN_OFF;              // 216 x 128 B, seg-swizzled
  float* offs = (float*)(smem + OFFS_OFF);   // [64][21]
  float* accx = (float*)(smem + ACCX_OFF);   // [64 o][68 px] (aliases xwin)

  int t = threadIdx.x;
  int blk = xcd_remap(blockIdx.x, NPIX / MT / NXCD);
  int b = blk / NTILE;
  int ti = blk % NTILE;
  int tr = ti / 3, tc = ti % 3;
  int h0 = tr * 2, w0 = tc * 32;
  int hw0 = h0 * WW + w0;

  const char* xb = (const char*)(xt + (size_t)b * HW * CC);

  // ---- P0: stage window, seg-swizzled, ZERO-fill out-of-image (R18) ----
  #pragma unroll
  for (int r = 0; r < 4; ++r) {
    int d = r * 512 + t;                     // 16-B chunk id, 1728 total
    if (d < NWIN * 8) {
      int row = d >> 3, sg = d & 7;
      int wr_ = row / WC, wc_ = row - wr_ * WC;
      int gy = h0 - 2 + wr_;
      int gx = w0 - 2 + wc_;
      uint4v v = (uint4v){0u, 0u, 0u, 0u};
      if (((unsigned)gy < HH) && ((unsigned)gx < WW))
        v = *(const uint4v*)(xb + (size_t)((gy * WW + gx) << 7) + (sg << 4));
      *(uint4v*)&xwin[row * 128 + ((sg ^ (row & 7)) << 4)] = v;
    }
  }
  __syncthreads();

  // wave geometry (verified R9/R12)
  int wv = t >> 6;
  int l  = t & 63;
  int lr = l & 15, lh = l >> 4;

  // ---- P1: offset conv via MFMA (R18-verified math; wofx B coalesced) ----
  {
    int m = wv & 3, n = wv >> 2;             // 4 pixel-tiles x 2 j-tiles
    int p = m * 16 + lr;
    int prow = ((p >> 5) + 1) * WC + (p & 31) + 1;  // window row at ky=kx=0
    f32x4 accO = (f32x4){0.f, 0.f, 0.f, 0.f};
    #pragma unroll
    for (int kt = 0; kt < K2; ++kt) {
      int wrow = prow + (kt / 3) * WC + (kt % 3);
      int rs = wrow & 7;
      const char* bp = (const char*)wofx + (((size_t)(kt * 2 + n) * 4) * 64 + l) * 8;
      #pragma unroll
      for (int q = 0; q < 4; ++q) {
        uint2v a2 = *(const uint2v*)&xwin[wrow * 128
                      + ((((q << 1) + (lh >> 1)) ^ rs) << 4) + ((lh & 1) << 3)];
        uint2v b2 = *(const uint2v*)(bp + (size_t)q * (64 * 8));
        accO = MFMA16(fq2(a2), fq2(b2), accO);
      }
    }
    int j = n * 16 + lr;
    if (j < NOFF) {
      float bj = b_off[j];
      #pragma unroll
      for (int r = 0; r < 4; ++r) {
        int px = m * 16 + lh * 4 + r;        // D row = pixel (R9 map)
        offs[px * OSTR + j] = accO[r] + bj;
      }
    }
  }
  __syncthreads();

  // ---- P2: per-lane params for this group's taps (R15/R17 math) ----
  int grp = wv >> 2;
  int base = grp * 5;                  // g0: taps 0..4, g1: taps 5..8
  int cnt  = 5 - grp;
  int Ra = (wv & 3) * 16 + lr;
  int hpix = h0 + (Ra >> 5), wpix = w0 + (Ra & 31);
  int cB = lh * 32;

  unsigned po01[5], po23[5], pw01[5], pw23[5];
  unsigned emask = 0;
  #pragma unroll
  for (int i = 0; i < 5; ++i) {
    po01[i] = 0; po23[i] = 0; pw01[i] = 0; pw23[i] = 0;
    if (i < cnt) {
      int kt = base + i;
      int ky = kt / 3, kx = kt % 3;
      float py = offs[Ra * OSTR + 2 * kt]     + (float)(hpix - 1 + ky);
      float px = offs[Ra * OSTR + 2 * kt + 1] + (float)(wpix - 1 + kx);
      float y0f = floorf(py), x0f = floorf(px);
      float wy = py - y0f, wx = px - x0f;
      int y0 = (int)y0f, x0 = (int)x0f;
      int y1 = y0 + 1, x1 = x0 + 1;
      bool vy0 = (unsigned)y0 < HH, vy1 = (unsigned)y1 < HH;
      bool vx0 = (unsigned)x0 < WW, vx1 = (unsigned)x1 < WW;
      int cy0 = min(max(y0, 0), HH - 1), cy1 = min(max(y1, 0), HH - 1);
      int cx0 = min(max(x0, 0), WW - 1), cx1 = min(max(x1, 0), WW - 1);
      float g00 = (1.f - wy) * (1.f - wx) * ((vy0 && vx0) ? 1.f : 0.f);
      float g01 = (1.f - wy) * wx         * ((vy0 && vx1) ? 1.f : 0.f);
      float g10 = wy * (1.f - wx)         * ((vy1 && vx0) ? 1.f : 0.f);
      float g11 = wy * wx                 * ((vy1 && vx1) ? 1.f : 0.f);
      int ry0 = cy0 - (h0 - 2), ry1 = cy1 - (h0 - 2);
      int rx0 = cx0 - (w0 - 2), rx1 = cx1 - (w0 - 2);
      bool inw = ((unsigned)ry0 < WR) && ((unsigned)ry1 < WR) &&
                 ((unsigned)rx0 < WC) && ((unsigned)rx1 < WC);
      if (inw) {
        po01[i] = (unsigned)((ry0 * WC + rx0) << 7)
                | ((unsigned)((ry0 * WC + rx1) << 7) << 16);
        po23[i] = (unsigned)((ry1 * WC + rx0) << 7)
                | ((unsigned)((ry1 * WC + rx1) << 7) << 16);
      } else {
        po01[i] = (unsigned)(cy0 * WW + cx0)
                | ((unsigned)(cy0 * WW + cx1) << 16) | 0x80000000u;
        po23[i] = (unsigned)(cy1 * WW + cx0)
                | ((unsigned)(cy1 * WW + cx1) << 16);
        emask |= 1u << i;
      }
      f16x2 wa = {(f16)g00, (f16)g01};
      f16x2 wb = {(f16)g10, (f16)g11};
      pw01[i] = bcu(wa);
      pw23[i] = bcu(wb);
    }
  }

  f32x4 acc[4];
  #pragma unroll
  for (int nb = 0; nb < 4; ++nb) acc[nb] = (f32x4){0.f, 0.f, 0.f, 0.f};

  // ---- P3: dcn taps (R19-verified: blend/MFMA + lane-exact wtx B) ----
  #define WREAD(bo, pos) (*(const uint4v*)&xwin[(bo) + ((pos) << 4)])
  if (__ballot(emask != 0) == 0ull) {
    #pragma unroll
    for (int i = 0; i < 5; ++i) {
      if (i < cnt) {
        unsigned e0 = po01[i], e1 = po23[i];
        int i0 = (int)(e0 & 0xffffu), i1 = (int)(e0 >> 16);
        int i2 = (int)(e1 & 0xffffu), i3 = (int)(e1 >> 16);
        int s0 = lh * 2;
        uint4v c0a = WREAD(i0, s0 ^ ((i0 >> 7) & 7));
        uint4v c0b = WREAD(i0, (s0 + 1) ^ ((i0 >> 7) & 7));
        uint4v c1a = WREAD(i1, s0 ^ ((i1 >> 7) & 7));
        uint4v c1b = WREAD(i1, (s0 + 1) ^ ((i1 >> 7) & 7));
        uint4v c2a = WREAD(i2, s0 ^ ((i2 >> 7) & 7));
        uint4v c2b = WREAD(i2, (s0 + 1) ^ ((i2 >> 7) & 7));
        uint4v c3a = WREAD(i3, s0 ^ ((i3 >> 7) & 7));
        uint4v c3b = WREAD(i3, (s0 + 1) ^ ((i3 >> 7) & 7));
        f16x2 wA = bch(pw01[i]), wB = bch(pw23[i]);
        f16x2 p0 = {wA[0], wA[0]}, p1 = {wA[1], wA[1]};
        f16x2 p2 = {wB[0], wB[0]}, p3 = {wB[1], wB[1]};
        uint4v pa, pb2;
        #pragma unroll
        for (int q = 0; q < 4; ++q) {
          f16x2 s  = p0 * bch(c0a[q]) + p1 * bch(c1a[q])
                   + p2 * bch(c2a[q]) + p3 * bch(c3a[q]);
          pa[q] = bcu(s);
          f16x2 s2 = p0 * bch(c0b[q]) + p1 * bch(c1b[q])
                   + p2 * bch(c2b[q]) + p3 * bch(c3b[q]);
          pb2[q] = bcu(s2);
        }
        f16x4 a0 = fq(pa[0],  pa[1]);
        f16x4 a1 = fq(pa[2],  pa[3]);
        f16x4 a2 = fq(pb2[0], pb2[1]);
        f16x4 a3 = fq(pb2[2], pb2[3]);
        const char* wbase = (const char*)wtx
                          + (((size_t)(base + i) * 4) * 64 + l) * 32;
        #pragma unroll
        for (int nb = 0; nb < 4; ++nb) {
          const char* wp = wbase + (size_t)nb * (64 * 32);
          uint4v u0 = *(const uint4v*)wp;
          uint4v u1 = *(const uint4v*)(wp + 16);
          acc[nb] = MFMA16(a0, fq(u0[0], u0[1]), acc[nb]);
          acc[nb] = MFMA16(a1, fq(u0[2], u0[3]), acc[nb]);
          acc[nb] = MFMA16(a2, fq(u1[0], u1[1]), acc[nb]);
          acc[nb] = MFMA16(a3, fq(u1[2], u1[3]), acc[nb]);
        }
      }
    }
  } else {
    #pragma unroll
    for (int i = 0; i < 5; ++i) {
      if (i < cnt) {
        unsigned e0 = po01[i], e1 = po23[i];
        uint4v c0a, c0b, c1a, c1b, c2a, c2b, c3a, c3b;
        if ((int)e0 >= 0) {
          int i0 = (int)(e0 & 0xffffu), i1 = (int)(e0 >> 16);
          int i2 = (int)(e1 & 0xffffu), i3 = (int)(e1 >> 16);
          int s0 = lh * 2;
          c0a = WREAD(i0, s0 ^ ((i0 >> 7) & 7));
          c0b = WREAD(i0, (s0 + 1) ^ ((i0 >> 7) & 7));
          c1a = WREAD(i1, s0 ^ ((i1 >> 7) & 7));
          c1b = WREAD(i1, (s0 + 1) ^ ((i1 >> 7) & 7));
          c2a = WREAD(i2, s0 ^ ((i2 >> 7) & 7));
          c2b = WREAD(i2, (s0 + 1) ^ ((i2 >> 7) & 7));
          c3a = WREAD(i3, s0 ^ ((i3 >> 7) & 7));
          c3b = WREAD(i3, (s0 + 1) ^ ((i3 >> 7) & 7));
        } else {
          int i0 = (int)(e0 & 0x7fffu) << 7;
          int i1 = (int)((e0 >> 16) & 0x7fffu) << 7;
          int i2 = (int)(e1 & 0x7fffu) << 7;
          int i3 = (int)((e1 >> 16) & 0x7fffu) << 7;
          c0a = *(const uint4v*)(xb + i0 + cB);
          c0b = *(const uint4v*)(xb + i0 + cB + 16);
          c1a = *(const uint4v*)(xb + i1 + cB);
          c1b = *(const uint4v*)(xb + i1 + cB + 16);
          c2a = *(const uint4v*)(xb + i2 + cB);
          c2b = *(const uint4v*)(xb + i2 + cB + 16);
          c3a = *(const uint4v*)(xb + i3 + cB);
          c3b = *(const uint4v*)(xb + i3 + cB + 16);
        }
        f16x2 wA = bch(pw01[i]), wB = bch(pw23[i]);
        f16x2 p0 = {wA[0], wA[0]}, p1 = {wA[1], wA[1]};
        f16x2 p2 = {wB[0], wB[0]}, p3 = {wB[1], wB[1]};
        uint4v pa, pb2;
        #pragma unroll
        for (int q = 0; q < 4; ++q) {
          f16x2 s  = p0 * bch(c0a[q]) + p1 * bch(c1a[q])
                   + p2 * bch(c2a[q]) + p3 * bch(c3a[q]);
          pa[q] = bcu(s);
          f16x2 s2 = p0 * bch(c0b[q]) + p1 * bch(c1b[q])
                   + p2 * bch(c2b[q]) + p3 * bch(c3b[q]);
          pb2[q] = bcu(s2);
        }
        f16x4 a0 = fq(pa[0],  pa[1]);
        f16x4 a1 = fq(pa[2],  pa[3]);
        f16x4 a2 = fq(pb2[0], pb2[1]);
        f16x4 a3 = fq(pb2[2], pb2[3]);
        const char* wbase = (const char*)wtx
                          + (((size_t)(base + i) * 4) * 64 + l) * 32;
        #pragma unroll
        for (int nb = 0; nb < 4; ++nb) {
          const char* wp = wbase + (size_t)nb * (64 * 32);
          uint4v u0 = *(const uint4v*)wp;
          uint4v u1 = *(const uint4v*)(wp + 16);
          acc[nb] = MFMA16(a0, fq(u0[0], u0[1]), acc[nb]);
          acc[nb] = MFMA16(a1, fq(u0[2], u0[3]), acc[nb]);
          acc[nb] = MFMA16(a2, fq(u1[0], u1[1]), acc[nb]);
          acc[nb] = MFMA16(a3, fq(u1[2], u1[3]), acc[nb]);
        }
      }
    }
  }
  __syncthreads();   // xwin dead; accx (alias) exchange

  // ---- P4: group1 -> accx, group0 adds + stores (verified R17/R18/R19) ----
  if (grp == 1) {
    #pragma unroll
    for (int nb = 0; nb < 4; ++nb)
      *(f32x4*)&accx[(nb * 16 + lr) * 68 + (wv & 3) * 16 + lh * 4] = acc[nb];
  }
  __syncthreads();
  if (grp == 0) {
    float* ob = out + (size_t)b * OO * HW;
    #pragma unroll
    for (int nb = 0; nb < 4; ++nb) {
      f32x4 other = *(const f32x4*)&accx[(nb * 16 + lr) * 68 + (wv & 3) * 16 + lh * 4];
      f32x4 v = acc[nb] + other;
      int o = nb * 16 + lr;
      int m = (wv & 3) * 16 + lh * 4;
      int base2 = hw0 + (m >> 5) * WW + (m & 31);
      *(f32x4*)(ob + (size_t)o * HW + base2) = v;
    }
  }
}

extern "C" void kernel_launch(void* const* d_in, const int* in_sizes, int n_in,
                              void* d_out, int out_size, void* d_ws, size_t ws_size,
                              hipStream_t stream) {
  const float* x     = (const float*)d_in[0];
  const float* w_off = (const float*)d_in[1];
  const float* b_off = (const float*)d_in[2];
  const float* w_dcn = (const float*)d_in[3];
  float* out = (float*)d_out;

  char* ws = (char*)d_ws;
  unsigned short* xtp  = (unsigned short*)ws;                     // 9,437,184 B
  unsigned short* wtx  = (unsigned short*)(ws + 9437184);         //    73,728 B
  unsigned short* wofx = (unsigned short*)(ws + 9437184 + 73728); //    36,864 B

  transpose_kernel<<<NPIX / 64, 256, 0, stream>>>(x, xtp);
  wprep_kernel<<<(K2 * 4 * 64 * 16) / 256, 256, 0, stream>>>(w_dcn, wtx);
  woffprep_kernel<<<(K2 * 2 * 4 * 64 * 4) / 256, 256, 0, stream>>>(w_off, wofx);
  fused_kernel<<<NPIX / MT, 512, 0, stream>>>(xtp, wofx, b_off, wtx, out);
}